// Round 1
// baseline (529.929 us; speedup 1.0000x reference)
//
#include <hip/hip_runtime.h>
#include <hip/hip_bf16.h>

// GNNEncoder: 3-layer GraphSAGE (mean agg) on N=50000 nodes, E=800000 edges.
// Restructure: h' = act( mean_agg(x@Wl) + x@(Wr+Ws) + (bl+bs) )  (matmul-first,
// valid by linearity of segment-mean). CSR built once per launch, reused 3x.
// edge_attr / edge_weight are unused by the reference.

#define LB __launch_bounds__

// ---------------- CSR build ----------------
__global__ LB(256) void hist_kernel(const int* __restrict__ dst, int* __restrict__ deg, int E) {
  int e = blockIdx.x * 256 + threadIdx.x;
  if (e < E) atomicAdd(&deg[dst[e]], 1);
}

__global__ LB(1024) void scan1_kernel(const int* __restrict__ deg, int* __restrict__ incl,
                                      int* __restrict__ bsums, int n) {
  __shared__ int buf[1024];
  int tid = threadIdx.x;
  int i = blockIdx.x * 1024 + tid;
  int v = (i < n) ? deg[i] : 0;
  buf[tid] = v;
  __syncthreads();
  for (int off = 1; off < 1024; off <<= 1) {
    int add = (tid >= off) ? buf[tid - off] : 0;
    __syncthreads();
    buf[tid] += add;
    __syncthreads();
  }
  if (i < n) incl[i] = buf[tid];
  if (tid == 1023) bsums[blockIdx.x] = buf[1023];
}

__global__ void scan2_kernel(int* bsums, int nb, int* total) {
  if (threadIdx.x == 0 && blockIdx.x == 0) {
    int acc = 0;
    for (int b = 0; b < nb; ++b) { int t = bsums[b]; bsums[b] = acc; acc += t; }
    *total = acc;
  }
}

__global__ LB(1024) void scan3_kernel(const int* __restrict__ deg, const int* __restrict__ bsums,
                                      int* __restrict__ row_ptr, int* __restrict__ cursor,
                                      float* __restrict__ scale, int n) {
  int i = blockIdx.x * 1024 + threadIdx.x;
  if (i < n) {
    int v = deg[i];
    int excl = row_ptr[i] - v + bsums[blockIdx.x];
    row_ptr[i] = excl;
    cursor[i] = excl;
    scale[i] = 1.0f / (float)(v > 1 ? v : 1);
  }
}

__global__ LB(256) void scatter_kernel(const int* __restrict__ src, const int* __restrict__ dst,
                                       int* __restrict__ cursor, int* __restrict__ srcs_sorted,
                                       int E) {
  int e = blockIdx.x * 256 + threadIdx.x;
  if (e < E) {
    int p = atomicAdd(&cursor[dst[e]], 1);
    srcs_sorted[p] = src[e];
  }
}

// ---------------- weight prep: Wcat = [Wl | Wr+Ws], bsum = bl+bs ----------------
__global__ LB(256) void build_wcat_kernel(const float* __restrict__ Wl, const float* __restrict__ Wr,
                                          const float* __restrict__ Ws, const float* __restrict__ bl,
                                          const float* __restrict__ bs, float* __restrict__ Wcat,
                                          float* __restrict__ bsum, int DO) {
  int idx = blockIdx.x * 256 + threadIdx.x;
  int M = 2 * DO;
  if (idx < 128 * DO) {
    int k = idx / DO, c = idx - k * DO;
    Wcat[(size_t)k * M + c] = Wl[idx];
    Wcat[(size_t)k * M + DO + c] = Wr[idx] + Ws[idx];
  }
  if (idx < DO) bsum[idx] = bl[idx] + bs[idx];
}

// ---------------- GEMM: C[n,M] = A[n,128] @ W[128,M] ----------------
// 64x64 tile / block, 256 threads, 4x4 per thread, K staged in two 64-halves.
template <int M>
__global__ LB(256) void gemm_kernel(const float* __restrict__ A, const float* __restrict__ W,
                                    float* __restrict__ C, int n) {
  constexpr int K = 128;
  constexpr int AS = 68;  // padded stride: 16B-aligned, a-reads only 2-way (free)
  __shared__ float As[64 * AS];
  __shared__ float Bs[64 * 64];
  const int tid = threadIdx.x;
  const int rowBase = blockIdx.x * 64;
  const int colBase = blockIdx.y * 64;
  const int tx = tid & 15, ty = tid >> 4;
  float acc[4][4] = {};

  for (int kk = 0; kk < K; kk += 64) {
    __syncthreads();
    // stage A half: 64 rows x 64 k
#pragma unroll
    for (int i = 0; i < 4; ++i) {
      int idx = tid + i * 256;           // 0..1023 float4 slots
      int r = idx >> 4;                  // 16 float4 per row
      int c4 = (idx & 15) << 2;
      float4 v = make_float4(0.f, 0.f, 0.f, 0.f);
      int gr = rowBase + r;
      if (gr < n) v = *(const float4*)(A + (size_t)gr * K + kk + c4);
      *(float4*)(As + r * AS + c4) = v;
    }
    // stage B half: 64 k x 64 cols
#pragma unroll
    for (int i = 0; i < 4; ++i) {
      int idx = tid + i * 256;
      int r = idx >> 4;
      int c4 = (idx & 15) << 2;
      float4 v = *(const float4*)(W + (size_t)(kk + r) * M + colBase + c4);
      *(float4*)(Bs + r * 64 + c4) = v;
    }
    __syncthreads();
#pragma unroll 8
    for (int k = 0; k < 64; ++k) {
      float4 b = *(const float4*)(Bs + k * 64 + tx * 4);
#pragma unroll
      for (int i = 0; i < 4; ++i) {
        float a = As[(ty * 4 + i) * AS + k];
        acc[i][0] += a * b.x;
        acc[i][1] += a * b.y;
        acc[i][2] += a * b.z;
        acc[i][3] += a * b.w;
      }
    }
  }
#pragma unroll
  for (int i = 0; i < 4; ++i) {
    int gr = rowBase + ty * 4 + i;
    if (gr < n)
      *(float4*)(C + (size_t)gr * M + colBase + tx * 4) =
          make_float4(acc[i][0], acc[i][1], acc[i][2], acc[i][3]);
  }
}

// ---------------- aggregation: out[n] = act(Z[n] + bias + scale_n * sum_e Y[src_e]) ----------------
// YZ layout: [n, 2*DO], Y = cols [0,DO), Z = cols [DO,2DO). One wave per node.
template <int DO, bool RELU>
__global__ LB(256) void agg_kernel(const float* __restrict__ YZ, const int* __restrict__ row_ptr,
                                   const int* __restrict__ srcs, const float* __restrict__ scale,
                                   const float* __restrict__ bsum, float* __restrict__ out, int n) {
  int node = blockIdx.x * 4 + (threadIdx.x >> 6);
  if (node >= n) return;
  int lane = threadIdx.x & 63;
  int e = row_ptr[node];
  int end = row_ptr[node + 1];
  float sc = scale[node];

  if (DO == 128) {
    const float2* Y2 = (const float2*)YZ;  // row stride = 128 float2
    float accx = 0.f, accy = 0.f;
    for (; e + 1 < end; e += 2) {
      int s0 = srcs[e], s1 = srcs[e + 1];
      float2 v0 = Y2[(size_t)s0 * 128 + lane];
      float2 v1 = Y2[(size_t)s1 * 128 + lane];
      accx += v0.x + v1.x;
      accy += v0.y + v1.y;
    }
    if (e < end) {
      int s = srcs[e];
      float2 v = Y2[(size_t)s * 128 + lane];
      accx += v.x;
      accy += v.y;
    }
    float2 z = Y2[(size_t)node * 128 + 64 + lane];
    float2 b = ((const float2*)bsum)[lane];
    float o0 = z.x + sc * accx + b.x;
    float o1 = z.y + sc * accy + b.y;
    if (RELU) {
      o0 = fmaxf(o0, 0.f);
      o1 = fmaxf(o1, 0.f);
    }
    ((float2*)out)[(size_t)node * 64 + lane] = make_float2(o0, o1);
  } else {  // DO == 64, row stride 128 floats
    float acc = 0.f;
    for (; e + 1 < end; e += 2) {
      int s0 = srcs[e], s1 = srcs[e + 1];
      acc += YZ[(size_t)s0 * 128 + lane] + YZ[(size_t)s1 * 128 + lane];
    }
    if (e < end) acc += YZ[(size_t)srcs[e] * 128 + lane];
    float z = YZ[(size_t)node * 128 + 64 + lane];
    float o = z + sc * acc + bsum[lane];
    if (RELU) o = fmaxf(o, 0.f);
    out[(size_t)node * 64 + lane] = o;
  }
}

// ---------------- launch ----------------
extern "C" void kernel_launch(void* const* d_in, const int* in_sizes, int n_in,
                              void* d_out, int out_size, void* d_ws, size_t ws_size,
                              hipStream_t stream) {
  const float* x = (const float*)d_in[0];
  const int* ei = (const int*)d_in[1];
  const int N = in_sizes[0] / 128;
  const int E = in_sizes[3];  // edge_weight has E elements
  const int* src = ei;
  const int* dst = ei + E;
  const float* Wl[3] = {(const float*)d_in[4], (const float*)d_in[9], (const float*)d_in[14]};
  const float* bl[3] = {(const float*)d_in[5], (const float*)d_in[10], (const float*)d_in[15]};
  const float* Wr[3] = {(const float*)d_in[6], (const float*)d_in[11], (const float*)d_in[16]};
  const float* Ws[3] = {(const float*)d_in[7], (const float*)d_in[12], (const float*)d_in[17]};
  const float* bs[3] = {(const float*)d_in[8], (const float*)d_in[13], (const float*)d_in[18]};

  size_t off = 0;
  auto carve = [&](size_t bytes) -> char* {
    char* p = (char*)d_ws + off;
    off += (bytes + 255) & ~(size_t)255;
    return p;
  };
  int* deg = (int*)carve((size_t)N * 4);
  int* row_ptr = (int*)carve((size_t)(N + 1) * 4);
  int* cursor = (int*)carve((size_t)N * 4);
  int* bsums = (int*)carve(256 * 4);
  float* scale = (float*)carve((size_t)N * 4);
  int* srcs = (int*)carve((size_t)E * 4);
  float* wcat = (float*)carve((size_t)128 * 256 * 4);
  float* bsum = (float*)carve(256 * 4);
  float* YZ = (float*)carve((size_t)N * 256 * 4);
  float* HA = (float*)carve((size_t)N * 128 * 4);
  (void)ws_size;
  (void)n_in;
  (void)out_size;

  hipMemsetAsync(deg, 0, (size_t)N * 4, stream);
  int gE = (E + 255) / 256;
  hist_kernel<<<gE, 256, 0, stream>>>(dst, deg, E);
  int nb = (N + 1023) / 1024;
  scan1_kernel<<<nb, 1024, 0, stream>>>(deg, row_ptr, bsums, N);
  scan2_kernel<<<1, 64, 0, stream>>>(bsums, nb, row_ptr + N);
  scan3_kernel<<<nb, 1024, 0, stream>>>(deg, bsums, row_ptr, cursor, scale, N);
  scatter_kernel<<<gE, 256, 0, stream>>>(src, dst, cursor, srcs, E);

  int gRows = (N + 63) / 64;
  int gAgg = (N + 3) / 4;

  // layer 0: x -> HA
  build_wcat_kernel<<<(128 * 128 + 255) / 256, 256, 0, stream>>>(Wl[0], Wr[0], Ws[0], bl[0], bs[0],
                                                                 wcat, bsum, 128);
  gemm_kernel<256><<<dim3(gRows, 4), 256, 0, stream>>>(x, wcat, YZ, N);
  agg_kernel<128, true><<<gAgg, 256, 0, stream>>>(YZ, row_ptr, srcs, scale, bsum, HA, N);

  // layer 1: HA -> HA
  build_wcat_kernel<<<(128 * 128 + 255) / 256, 256, 0, stream>>>(Wl[1], Wr[1], Ws[1], bl[1], bs[1],
                                                                 wcat, bsum, 128);
  gemm_kernel<256><<<dim3(gRows, 4), 256, 0, stream>>>(HA, wcat, YZ, N);
  agg_kernel<128, true><<<gAgg, 256, 0, stream>>>(YZ, row_ptr, srcs, scale, bsum, HA, N);

  // layer 2: HA -> d_out (no relu)
  build_wcat_kernel<<<(128 * 64 + 255) / 256, 256, 0, stream>>>(Wl[2], Wr[2], Ws[2], bl[2], bs[2],
                                                                wcat, bsum, 64);
  gemm_kernel<128><<<dim3(gRows, 2), 256, 0, stream>>>(HA, wcat, YZ, N);
  agg_kernel<64, false><<<gAgg, 256, 0, stream>>>(YZ, row_ptr, srcs, scale, bsum, (float*)d_out, N);
}

// Round 2
// 441.499 us; speedup vs baseline: 1.2003x; 1.2003x over previous
//
#include <hip/hip_runtime.h>
#include <hip/hip_bf16.h>

// GNNEncoder: 3-layer GraphSAGE (mean agg), N=50000, E=800000.
// h' = act( mean_agg(x@Wl) + x@(Wr+Ws) + (bl+bs) )   (matmul-first by linearity)
// R2: GEMMs via bf16 MFMA with split hi/lo operands (3 MFMA ~ fp32 accuracy),
//     gather branch Y stored bf16 (halves gather bytes), self branch Z fp32.

#define LB __launch_bounds__

typedef __attribute__((ext_vector_type(8))) short short8;
typedef __attribute__((ext_vector_type(4))) float f32x4;

__device__ __forceinline__ unsigned short bf16_rne(float f) {
  unsigned u = __builtin_bit_cast(unsigned, f);
  unsigned r = u + 0x7fffu + ((u >> 16) & 1u);
  return (unsigned short)(r >> 16);
}
__device__ __forceinline__ float bf16_to_f(unsigned short us) {
  return __builtin_bit_cast(float, (unsigned)us << 16);
}
__device__ __forceinline__ float bits_to_f(unsigned u) {
  return __builtin_bit_cast(float, u);
}

// ---------------- CSR build ----------------
__global__ LB(256) void hist_kernel(const int* __restrict__ dst, int* __restrict__ deg, int E) {
  int e = blockIdx.x * 256 + threadIdx.x;
  if (e < E) atomicAdd(&deg[dst[e]], 1);
}

__global__ LB(1024) void scan1_kernel(const int* __restrict__ deg, int* __restrict__ incl,
                                      int* __restrict__ bsums, int n) {
  __shared__ int buf[1024];
  int tid = threadIdx.x;
  int i = blockIdx.x * 1024 + tid;
  int v = (i < n) ? deg[i] : 0;
  buf[tid] = v;
  __syncthreads();
  for (int off = 1; off < 1024; off <<= 1) {
    int add = (tid >= off) ? buf[tid - off] : 0;
    __syncthreads();
    buf[tid] += add;
    __syncthreads();
  }
  if (i < n) incl[i] = buf[tid];
  if (tid == 1023) bsums[blockIdx.x] = buf[1023];
}

__global__ void scan2_kernel(int* bsums, int nb, int* total) {
  if (threadIdx.x == 0 && blockIdx.x == 0) {
    int acc = 0;
    for (int b = 0; b < nb; ++b) { int t = bsums[b]; bsums[b] = acc; acc += t; }
    *total = acc;
  }
}

__global__ LB(1024) void scan3_kernel(const int* __restrict__ deg, const int* __restrict__ bsums,
                                      int* __restrict__ row_ptr, int* __restrict__ cursor,
                                      float* __restrict__ scale, int n) {
  int i = blockIdx.x * 1024 + threadIdx.x;
  if (i < n) {
    int v = deg[i];
    int excl = row_ptr[i] - v + bsums[blockIdx.x];
    row_ptr[i] = excl;
    cursor[i] = excl;
    scale[i] = 1.0f / (float)(v > 1 ? v : 1);
  }
}

__global__ LB(256) void scatter_kernel(const int* __restrict__ src, const int* __restrict__ dst,
                                       int* __restrict__ cursor, int* __restrict__ srcs_sorted,
                                       int E) {
  int e = blockIdx.x * 256 + threadIdx.x;
  if (e < E) {
    int p = atomicAdd(&cursor[dst[e]], 1);
    srcs_sorted[p] = src[e];
  }
}

// ---------------- x -> hi/lo bf16 planes ----------------
__global__ LB(256) void xpack_kernel(const float* __restrict__ x, ushort* __restrict__ hi,
                                     ushort* __restrict__ lo, int total4) {
  int i = blockIdx.x * 256 + threadIdx.x;
  if (i >= total4) return;
  float4 v = ((const float4*)x)[i];
  float f[4] = {v.x, v.y, v.z, v.w};
  ushort4 h, l;
  unsigned short hh[4], ll[4];
#pragma unroll
  for (int j = 0; j < 4; ++j) {
    hh[j] = bf16_rne(f[j]);
    ll[j] = bf16_rne(f[j] - bf16_to_f(hh[j]));
  }
  h.x = hh[0]; h.y = hh[1]; h.z = hh[2]; h.w = hh[3];
  l.x = ll[0]; l.y = ll[1]; l.z = ll[2]; l.w = ll[3];
  ((ushort4*)hi)[i] = h;
  ((ushort4*)lo)[i] = l;
}

// ---------------- weights -> fragment-ordered hi/lo bf16 + fused bias ----------------
// Packed layout: element (k,c) of Wcat[128,M] at index ((k>>3)*M + c)*8 + (k&7),
// so a lane's 8 k-consecutive values for one col are 16 B contiguous.
template <int M>
__global__ LB(256) void wpack_kernel(const float* __restrict__ Wl, const float* __restrict__ Wr,
                                     const float* __restrict__ Ws, const float* __restrict__ bl,
                                     const float* __restrict__ bs, ushort* __restrict__ Bhi,
                                     ushort* __restrict__ Blo, float* __restrict__ bsum) {
  constexpr int DO = M / 2;
  int idx = blockIdx.x * 256 + threadIdx.x;
  if (idx < 128 * M) {
    int k = idx / M, c = idx - k * M;
    float v = (c < DO) ? Wl[k * DO + c] : (Wr[k * DO + (c - DO)] + Ws[k * DO + (c - DO)]);
    unsigned short h = bf16_rne(v);
    unsigned short l = bf16_rne(v - bf16_to_f(h));
    int d = ((k >> 3) * M + c) * 8 + (k & 7);
    Bhi[d] = h;
    Blo[d] = l;
  }
  if (idx < DO) bsum[idx] = bl[idx] + bs[idx];
}

// ---------------- MFMA GEMM: [n,128](hi+lo bf16) @ [128,M] -> Y bf16 | Z fp32 ----------------
// Block: 256 thr = 4 waves in 2x2, tile 128x128. Wave tile 64x64 = 4x4 frags of 16x16x32.
// LDS-free: A frags 16B/lane from global (4 quads consume full 64B lines); B packed, L2-hit.
template <int M>
__global__ LB(256, 2) void mfma_gemm_kernel(const ushort* __restrict__ Ahi,
                                            const ushort* __restrict__ Alo,
                                            const ushort* __restrict__ Bhi,
                                            const ushort* __restrict__ Blo,
                                            ushort* __restrict__ Yb, float* __restrict__ Z, int n) {
  constexpr int DO = M / 2;
  const int tid = threadIdx.x;
  const int w = tid >> 6, l = tid & 63;
  const int q = l >> 4, m16 = l & 15;
  const int rowBase = blockIdx.x * 128 + (w >> 1) * 64;
  const int colBase = blockIdx.y * 128 + (w & 1) * 64;

  f32x4 acc[4][4] = {};
  int rrow[4];
#pragma unroll
  for (int i = 0; i < 4; ++i) {
    int r = rowBase + i * 16 + m16;
    rrow[i] = r < n ? r : n - 1;
  }

#pragma unroll
  for (int s = 0; s < 4; ++s) {
    const int ka = s * 32 + q * 8;
    short8 ah[4], al[4], bh[4], bo[4];
#pragma unroll
    for (int i = 0; i < 4; ++i) {
      size_t off = (size_t)rrow[i] * 128 + ka;
      ah[i] = *(const short8*)(Ahi + off);
      al[i] = *(const short8*)(Alo + off);
    }
    const int kb = s * 4 + q;
#pragma unroll
    for (int j = 0; j < 4; ++j) {
      size_t off = ((size_t)kb * M + colBase + j * 16 + m16) * 8;
      bh[j] = *(const short8*)(Bhi + off);
      bo[j] = *(const short8*)(Blo + off);
    }
#pragma unroll
    for (int i = 0; i < 4; ++i)
#pragma unroll
      for (int j = 0; j < 4; ++j) {
        acc[i][j] = __builtin_amdgcn_mfma_f32_16x16x32_bf16(ah[i], bh[j], acc[i][j], 0, 0, 0);
        acc[i][j] = __builtin_amdgcn_mfma_f32_16x16x32_bf16(ah[i], bo[j], acc[i][j], 0, 0, 0);
        acc[i][j] = __builtin_amdgcn_mfma_f32_16x16x32_bf16(al[i], bh[j], acc[i][j], 0, 0, 0);
      }
  }

#pragma unroll
  for (int i = 0; i < 4; ++i) {
    int rb = rowBase + i * 16 + q * 4;
#pragma unroll
    for (int j = 0; j < 4; ++j) {
      int c = colBase + j * 16 + m16;
#pragma unroll
      for (int r = 0; r < 4; ++r) {
        int row = rb + r;
        if (row < n) {
          float v = acc[i][j][r];
          if (c < DO)
            Yb[(size_t)row * DO + c] = bf16_rne(v);
          else
            Z[(size_t)row * DO + (c - DO)] = v;
        }
      }
    }
  }
}

// ---------------- aggregation ----------------
// DO=128: out H (hi/lo planes, packed 2 cols/lane). Y bf16 [n,128], Z fp32 [n,128].
__global__ LB(256) void agg128_kernel(const ushort* __restrict__ Y, const float* __restrict__ Z,
                                      const int* __restrict__ row_ptr, const int* __restrict__ srcs,
                                      const float* __restrict__ scale,
                                      const float* __restrict__ bsum, unsigned* __restrict__ Hhi,
                                      unsigned* __restrict__ Hlo, int n) {
  int node = blockIdx.x * 4 + (threadIdx.x >> 6);
  if (node >= n) return;
  int lane = threadIdx.x & 63;
  const unsigned* Yu = (const unsigned*)Y;  // row = 64 uints (2 bf16 each)
  int e = row_ptr[node], end = row_ptr[node + 1];
  float ax = 0.f, ay = 0.f;
  for (; e + 3 < end; e += 4) {
    int s0 = srcs[e], s1 = srcs[e + 1], s2 = srcs[e + 2], s3 = srcs[e + 3];
    unsigned u0 = Yu[(size_t)s0 * 64 + lane];
    unsigned u1 = Yu[(size_t)s1 * 64 + lane];
    unsigned u2 = Yu[(size_t)s2 * 64 + lane];
    unsigned u3 = Yu[(size_t)s3 * 64 + lane];
    ax += bits_to_f(u0 << 16) + bits_to_f(u1 << 16) + bits_to_f(u2 << 16) + bits_to_f(u3 << 16);
    ay += bits_to_f(u0 & 0xffff0000u) + bits_to_f(u1 & 0xffff0000u) + bits_to_f(u2 & 0xffff0000u) +
          bits_to_f(u3 & 0xffff0000u);
  }
  for (; e < end; ++e) {
    unsigned u = Yu[(size_t)srcs[e] * 64 + lane];
    ax += bits_to_f(u << 16);
    ay += bits_to_f(u & 0xffff0000u);
  }
  float sc = scale[node];
  float2 z = ((const float2*)Z)[(size_t)node * 64 + lane];
  float2 b = ((const float2*)bsum)[lane];
  float o0 = fmaxf(z.x + sc * ax + b.x, 0.f);
  float o1 = fmaxf(z.y + sc * ay + b.y, 0.f);
  unsigned short h0 = bf16_rne(o0);
  unsigned short l0 = bf16_rne(o0 - bf16_to_f(h0));
  unsigned short h1 = bf16_rne(o1);
  unsigned short l1 = bf16_rne(o1 - bf16_to_f(h1));
  Hhi[(size_t)node * 64 + lane] = (unsigned)h0 | ((unsigned)h1 << 16);
  Hlo[(size_t)node * 64 + lane] = (unsigned)l0 | ((unsigned)l1 << 16);
}

// DO=64 final layer: Y bf16 [n,64], Z fp32 [n,64], out fp32 [n,64], no relu.
__global__ LB(256) void agg64_kernel(const ushort* __restrict__ Y, const float* __restrict__ Z,
                                     const int* __restrict__ row_ptr, const int* __restrict__ srcs,
                                     const float* __restrict__ scale, const float* __restrict__ bsum,
                                     float* __restrict__ out, int n) {
  int node = blockIdx.x * 4 + (threadIdx.x >> 6);
  if (node >= n) return;
  int lane = threadIdx.x & 63;
  int e = row_ptr[node], end = row_ptr[node + 1];
  float a = 0.f;
  for (; e + 3 < end; e += 4) {
    int s0 = srcs[e], s1 = srcs[e + 1], s2 = srcs[e + 2], s3 = srcs[e + 3];
    a += bf16_to_f(Y[(size_t)s0 * 64 + lane]) + bf16_to_f(Y[(size_t)s1 * 64 + lane]) +
         bf16_to_f(Y[(size_t)s2 * 64 + lane]) + bf16_to_f(Y[(size_t)s3 * 64 + lane]);
  }
  for (; e < end; ++e) a += bf16_to_f(Y[(size_t)srcs[e] * 64 + lane]);
  float o = Z[(size_t)node * 64 + lane] + scale[node] * a + bsum[lane];
  out[(size_t)node * 64 + lane] = o;
}

// ---------------- launch ----------------
extern "C" void kernel_launch(void* const* d_in, const int* in_sizes, int n_in,
                              void* d_out, int out_size, void* d_ws, size_t ws_size,
                              hipStream_t stream) {
  const float* x = (const float*)d_in[0];
  const int* ei = (const int*)d_in[1];
  const int N = in_sizes[0] / 128;
  const int E = in_sizes[3];
  const int* src = ei;
  const int* dst = ei + E;
  const float* Wl[3] = {(const float*)d_in[4], (const float*)d_in[9], (const float*)d_in[14]};
  const float* bl[3] = {(const float*)d_in[5], (const float*)d_in[10], (const float*)d_in[15]};
  const float* Wr[3] = {(const float*)d_in[6], (const float*)d_in[11], (const float*)d_in[16]};
  const float* Ws[3] = {(const float*)d_in[7], (const float*)d_in[12], (const float*)d_in[17]};
  const float* bs[3] = {(const float*)d_in[8], (const float*)d_in[13], (const float*)d_in[18]};

  size_t off = 0;
  auto carve = [&](size_t bytes) -> char* {
    char* p = (char*)d_ws + off;
    off += (bytes + 255) & ~(size_t)255;
    return p;
  };
  int* deg = (int*)carve((size_t)N * 4);
  int* row_ptr = (int*)carve((size_t)(N + 1) * 4);
  int* cursor = (int*)carve((size_t)N * 4);
  int* bsums = (int*)carve(256 * 4);
  float* scale = (float*)carve((size_t)N * 4);
  int* srcs = (int*)carve((size_t)E * 4);
  ushort* Xhi = (ushort*)carve((size_t)N * 128 * 2);
  ushort* Xlo = (ushort*)carve((size_t)N * 128 * 2);
  ushort* Hhi = (ushort*)carve((size_t)N * 128 * 2);
  ushort* Hlo = (ushort*)carve((size_t)N * 128 * 2);
  ushort* Yb = (ushort*)carve((size_t)N * 128 * 2);
  float* Zf = (float*)carve((size_t)N * 128 * 4);
  ushort* Bh[3];
  ushort* Bo[3];
  float* bsum[3];
  for (int i = 0; i < 3; ++i) {
    Bh[i] = (ushort*)carve(128 * 256 * 2);
    Bo[i] = (ushort*)carve(128 * 256 * 2);
    bsum[i] = (float*)carve(128 * 4);
  }
  (void)ws_size;
  (void)n_in;
  (void)out_size;

  // CSR
  hipMemsetAsync(deg, 0, (size_t)N * 4, stream);
  int gE = (E + 255) / 256;
  hist_kernel<<<gE, 256, 0, stream>>>(dst, deg, E);
  int nb = (N + 1023) / 1024;
  scan1_kernel<<<nb, 1024, 0, stream>>>(deg, row_ptr, bsums, N);
  scan2_kernel<<<1, 64, 0, stream>>>(bsums, nb, row_ptr + N);
  scan3_kernel<<<nb, 1024, 0, stream>>>(deg, bsums, row_ptr, cursor, scale, N);
  scatter_kernel<<<gE, 256, 0, stream>>>(src, dst, cursor, srcs, E);

  // packing
  xpack_kernel<<<(N * 32 + 255) / 256, 256, 0, stream>>>(x, Xhi, Xlo, N * 32);
  wpack_kernel<256><<<(128 * 256 + 255) / 256, 256, 0, stream>>>(Wl[0], Wr[0], Ws[0], bl[0], bs[0],
                                                                 Bh[0], Bo[0], bsum[0]);
  wpack_kernel<256><<<(128 * 256 + 255) / 256, 256, 0, stream>>>(Wl[1], Wr[1], Ws[1], bl[1], bs[1],
                                                                 Bh[1], Bo[1], bsum[1]);
  wpack_kernel<128><<<(128 * 128 + 255) / 256, 256, 0, stream>>>(Wl[2], Wr[2], Ws[2], bl[2], bs[2],
                                                                 Bh[2], Bo[2], bsum[2]);

  int G = (N + 127) / 128;
  int gAgg = (N + 3) / 4;

  // layer 0
  mfma_gemm_kernel<256><<<dim3(G, 2), 256, 0, stream>>>(Xhi, Xlo, Bh[0], Bo[0], Yb, Zf, N);
  agg128_kernel<<<gAgg, 256, 0, stream>>>(Yb, Zf, row_ptr, srcs, scale, bsum[0], (unsigned*)Hhi,
                                          (unsigned*)Hlo, N);
  // layer 1
  mfma_gemm_kernel<256><<<dim3(G, 2), 256, 0, stream>>>(Hhi, Hlo, Bh[1], Bo[1], Yb, Zf, N);
  agg128_kernel<<<gAgg, 256, 0, stream>>>(Yb, Zf, row_ptr, srcs, scale, bsum[1], (unsigned*)Hhi,
                                          (unsigned*)Hlo, N);
  // layer 2
  mfma_gemm_kernel<128><<<dim3(G, 1), 256, 0, stream>>>(Hhi, Hlo, Bh[2], Bo[2], Yb, Zf, N);
  agg64_kernel<<<gAgg, 256, 0, stream>>>(Yb, Zf, row_ptr, srcs, scale, bsum[2], (float*)d_out, N);
}

// Round 3
// 370.995 us; speedup vs baseline: 1.4284x; 1.1900x over previous
//
#include <hip/hip_runtime.h>
#include <hip/hip_bf16.h>

// GNNEncoder: 3-layer GraphSAGE (mean agg), N=50000, E=800000.
// h' = act( mean_agg(x@Wl) + x@(Wr+Ws) + (bl+bs) )   (matmul-first by linearity)
// R3: LDS-ranked bucket sort for CSR (kills random scatter line-allocate),
//     xpack fused into GEMM-0 (in-reg hi/lo split), 64x256 GEMM block tile
//     (A read once), wpack fused to one launch.

#define LB __launch_bounds__

typedef __attribute__((ext_vector_type(8))) short short8;
typedef __attribute__((ext_vector_type(4))) float f32x4;

__device__ __forceinline__ unsigned short bf16_rne(float f) {
  unsigned u = __builtin_bit_cast(unsigned, f);
  unsigned r = u + 0x7fffu + ((u >> 16) & 1u);
  return (unsigned short)(r >> 16);
}
__device__ __forceinline__ float bf16_to_f(unsigned short us) {
  return __builtin_bit_cast(float, (unsigned)us << 16);
}
__device__ __forceinline__ float bits_to_f(unsigned u) {
  return __builtin_bit_cast(float, u);
}

// ---------------- CSR build: bucketed 2-pass sort ----------------
// bucket b = dst >> 8 (256 nodes/bucket). NB = ceil(N/256) = 196 <= 256.
#define BCAP 8192
#define P1_CHUNK 4096

__global__ LB(256) void p1_bucket(const int* __restrict__ src, const int* __restrict__ dst,
                                  int* __restrict__ bcnt, int2* __restrict__ pairs, int E) {
  __shared__ int cnt[256];
  __shared__ int base[256];
  const int tid = threadIdx.x;
  cnt[tid] = 0;
  __syncthreads();
  const int e0 = blockIdx.x * P1_CHUNK;
  int myb[16], myr[16], mys[16], myd[16];
#pragma unroll
  for (int i = 0; i < 16; ++i) {
    int e = e0 + i * 256 + tid;
    myb[i] = -1;
    if (e < E) {
      int s = src[e], d = dst[e];
      int b = d >> 8;
      myb[i] = b;
      mys[i] = s;
      myd[i] = d;
      myr[i] = atomicAdd(&cnt[b], 1);
    }
  }
  __syncthreads();
  base[tid] = (cnt[tid] > 0) ? atomicAdd(&bcnt[tid], cnt[tid]) : 0;
  __syncthreads();
#pragma unroll
  for (int i = 0; i < 16; ++i) {
    int b = myb[i];
    if (b >= 0) {
      int p = base[b] + myr[i];
      if (p < BCAP) pairs[(size_t)b * BCAP + p] = make_int2(mys[i], myd[i]);
    }
  }
}

__global__ LB(256) void p2_hist(const int2* __restrict__ pairs, const int* __restrict__ bcnt,
                                int* __restrict__ deg, int N) {
  __shared__ int h[256];
  const int tid = threadIdx.x;
  const int b = blockIdx.x;
  h[tid] = 0;
  __syncthreads();
  int m = bcnt[b];
  if (m > BCAP) m = BCAP;
  for (int i = tid; i < m; i += 256) {
    int d = pairs[(size_t)b * BCAP + i].y;
    atomicAdd(&h[d & 255], 1);
  }
  __syncthreads();
  int node = b * 256 + tid;
  if (node < N) deg[node] = h[tid];
}

__global__ LB(1024) void scan1_kernel(const int* __restrict__ deg, int* __restrict__ incl,
                                      int* __restrict__ bsums, int n) {
  __shared__ int buf[1024];
  int tid = threadIdx.x;
  int i = blockIdx.x * 1024 + tid;
  int v = (i < n) ? deg[i] : 0;
  buf[tid] = v;
  __syncthreads();
  for (int off = 1; off < 1024; off <<= 1) {
    int add = (tid >= off) ? buf[tid - off] : 0;
    __syncthreads();
    buf[tid] += add;
    __syncthreads();
  }
  if (i < n) incl[i] = buf[tid];
  if (tid == 1023) bsums[blockIdx.x] = buf[1023];
}

__global__ void scan2_kernel(int* bsums, int nb, int* total) {
  if (threadIdx.x == 0 && blockIdx.x == 0) {
    int acc = 0;
    for (int b = 0; b < nb; ++b) { int t = bsums[b]; bsums[b] = acc; acc += t; }
    *total = acc;
  }
}

__global__ LB(1024) void scan3_kernel(const int* __restrict__ deg, const int* __restrict__ bsums,
                                      int* __restrict__ row_ptr, float* __restrict__ scale, int n) {
  int i = blockIdx.x * 1024 + threadIdx.x;
  if (i < n) {
    int v = deg[i];
    row_ptr[i] = row_ptr[i] - v + bsums[blockIdx.x];
    scale[i] = 1.0f / (float)(v > 1 ? v : 1);
  }
}

__global__ LB(256) void p4_place(const int2* __restrict__ pairs, const int* __restrict__ bcnt,
                                 const int* __restrict__ row_ptr, int* __restrict__ srcs, int N) {
  __shared__ int cur[256];
  const int tid = threadIdx.x;
  const int b = blockIdx.x;
  int node = b * 256 + tid;
  cur[tid] = (node < N) ? row_ptr[node] : 0;
  __syncthreads();
  int m = bcnt[b];
  if (m > BCAP) m = BCAP;
  for (int i = tid; i < m; i += 256) {
    int2 pr = pairs[(size_t)b * BCAP + i];
    int p = atomicAdd(&cur[pr.y & 255], 1);
    srcs[p] = pr.x;
  }
}

// ---------------- weights -> fragment-ordered hi/lo bf16 + fused bias ----------------
// Packed: element (k,c) of Wcat[128,M] at ((k>>3)*M + c)*8 + (k&7).
__global__ LB(256) void wpack_all(const float* __restrict__ Wl0, const float* __restrict__ Wr0,
                                  const float* __restrict__ Ws0, const float* __restrict__ bl0,
                                  const float* __restrict__ bs0, const float* __restrict__ Wl1,
                                  const float* __restrict__ Wr1, const float* __restrict__ Ws1,
                                  const float* __restrict__ bl1, const float* __restrict__ bs1,
                                  const float* __restrict__ Wl2, const float* __restrict__ Wr2,
                                  const float* __restrict__ Ws2, const float* __restrict__ bl2,
                                  const float* __restrict__ bs2, ushort* __restrict__ Bh0,
                                  ushort* __restrict__ Bo0, float* __restrict__ bb0,
                                  ushort* __restrict__ Bh1, ushort* __restrict__ Bo1,
                                  float* __restrict__ bb1, ushort* __restrict__ Bh2,
                                  ushort* __restrict__ Bo2, float* __restrict__ bb2) {
  const int layer = blockIdx.y;
  const float *Wl, *Wr, *Ws, *bl, *bs;
  ushort *Bh, *Bo;
  float* bb;
  int M;
  if (layer == 0) {
    Wl = Wl0; Wr = Wr0; Ws = Ws0; bl = bl0; bs = bs0; Bh = Bh0; Bo = Bo0; bb = bb0; M = 256;
  } else if (layer == 1) {
    Wl = Wl1; Wr = Wr1; Ws = Ws1; bl = bl1; bs = bs1; Bh = Bh1; Bo = Bo1; bb = bb1; M = 256;
  } else {
    Wl = Wl2; Wr = Wr2; Ws = Ws2; bl = bl2; bs = bs2; Bh = Bh2; Bo = Bo2; bb = bb2; M = 128;
  }
  const int DO = M / 2;
  int idx = blockIdx.x * 256 + threadIdx.x;
  if (idx < 128 * M) {
    int k = idx / M, c = idx - k * M;
    float v = (c < DO) ? Wl[k * DO + c] : (Wr[k * DO + (c - DO)] + Ws[k * DO + (c - DO)]);
    unsigned short h = bf16_rne(v);
    unsigned short l = bf16_rne(v - bf16_to_f(h));
    int d = ((k >> 3) * M + c) * 8 + (k & 7);
    Bh[d] = h;
    Bo[d] = l;
  }
  if (idx < DO) bb[idx] = bl[idx] + bs[idx];
}

// ---------------- MFMA GEMM ----------------
// A[n,128] (fp32 if AFP32 else hi/lo bf16 planes) @ Wcat[128,M] -> Y bf16 | Z fp32.
// Block: 4 waves. M=256: 1x4 wave grid (64 rows x 256 cols, A read once).
// M=128: 2x2 (128 rows x 128 cols). Wave tile 64x64 = 4x4 frags of 16x16x32.
__device__ __forceinline__ void split8(const float* __restrict__ p, short8& h, short8& l) {
  float4 f0 = *(const float4*)p;
  float4 f1 = *(const float4*)(p + 4);
  float f[8] = {f0.x, f0.y, f0.z, f0.w, f1.x, f1.y, f1.z, f1.w};
#pragma unroll
  for (int j = 0; j < 8; ++j) {
    unsigned u = __builtin_bit_cast(unsigned, f[j]);
    h[j] = (short)(u >> 16);
    l[j] = (short)bf16_rne(f[j] - bits_to_f(u & 0xffff0000u));
  }
}

template <int M, bool AFP32>
__global__ LB(256, 2) void mfma_gemm_kernel(const float* __restrict__ Af,
                                            const ushort* __restrict__ Ahi,
                                            const ushort* __restrict__ Alo,
                                            const ushort* __restrict__ Bhi,
                                            const ushort* __restrict__ Blo,
                                            ushort* __restrict__ Yb, float* __restrict__ Z, int n) {
  constexpr int DO = M / 2;
  constexpr int NWC = M / 64;       // waves along cols
  constexpr int NWR = 4 / NWC;      // waves along rows
  const int tid = threadIdx.x;
  const int w = tid >> 6, l = tid & 63;
  const int q = l >> 4, m16 = l & 15;
  const int rowBase = blockIdx.x * (64 * NWR) + (w / NWC) * 64;
  const int colBase = (w % NWC) * 64;

  f32x4 acc[4][4] = {};
  int rrow[4];
#pragma unroll
  for (int i = 0; i < 4; ++i) {
    int r = rowBase + i * 16 + m16;
    rrow[i] = r < n ? r : n - 1;
  }

#pragma unroll
  for (int s = 0; s < 4; ++s) {
    const int ka = s * 32 + q * 8;
    short8 ah[4], al[4], bh[4], bo[4];
#pragma unroll
    for (int i = 0; i < 4; ++i) {
      size_t off = (size_t)rrow[i] * 128 + ka;
      if (AFP32) {
        split8(Af + off, ah[i], al[i]);
      } else {
        ah[i] = *(const short8*)(Ahi + off);
        al[i] = *(const short8*)(Alo + off);
      }
    }
    const int kb = s * 4 + q;
#pragma unroll
    for (int j = 0; j < 4; ++j) {
      size_t off = ((size_t)kb * M + colBase + j * 16 + m16) * 8;
      bh[j] = *(const short8*)(Bhi + off);
      bo[j] = *(const short8*)(Blo + off);
    }
#pragma unroll
    for (int i = 0; i < 4; ++i)
#pragma unroll
      for (int j = 0; j < 4; ++j) {
        acc[i][j] = __builtin_amdgcn_mfma_f32_16x16x32_bf16(ah[i], bh[j], acc[i][j], 0, 0, 0);
        acc[i][j] = __builtin_amdgcn_mfma_f32_16x16x32_bf16(ah[i], bo[j], acc[i][j], 0, 0, 0);
        acc[i][j] = __builtin_amdgcn_mfma_f32_16x16x32_bf16(al[i], bh[j], acc[i][j], 0, 0, 0);
      }
  }

#pragma unroll
  for (int i = 0; i < 4; ++i) {
    int rb = rowBase + i * 16 + q * 4;
#pragma unroll
    for (int j = 0; j < 4; ++j) {
      int c = colBase + j * 16 + m16;
#pragma unroll
      for (int r = 0; r < 4; ++r) {
        int row = rb + r;
        if (row < n) {
          float v = acc[i][j][r];
          if (c < DO)
            Yb[(size_t)row * DO + c] = bf16_rne(v);
          else
            Z[(size_t)row * DO + (c - DO)] = v;
        }
      }
    }
  }
}

// ---------------- aggregation ----------------
__global__ LB(256) void agg128_kernel(const ushort* __restrict__ Y, const float* __restrict__ Z,
                                      const int* __restrict__ row_ptr, const int* __restrict__ srcs,
                                      const float* __restrict__ scale,
                                      const float* __restrict__ bsum, unsigned* __restrict__ Hhi,
                                      unsigned* __restrict__ Hlo, int n) {
  int node = blockIdx.x * 4 + (threadIdx.x >> 6);
  if (node >= n) return;
  int lane = threadIdx.x & 63;
  const unsigned* Yu = (const unsigned*)Y;
  int e = row_ptr[node], end = row_ptr[node + 1];
  float ax = 0.f, ay = 0.f;
  for (; e + 3 < end; e += 4) {
    int s0 = srcs[e], s1 = srcs[e + 1], s2 = srcs[e + 2], s3 = srcs[e + 3];
    unsigned u0 = Yu[(size_t)s0 * 64 + lane];
    unsigned u1 = Yu[(size_t)s1 * 64 + lane];
    unsigned u2 = Yu[(size_t)s2 * 64 + lane];
    unsigned u3 = Yu[(size_t)s3 * 64 + lane];
    ax += bits_to_f(u0 << 16) + bits_to_f(u1 << 16) + bits_to_f(u2 << 16) + bits_to_f(u3 << 16);
    ay += bits_to_f(u0 & 0xffff0000u) + bits_to_f(u1 & 0xffff0000u) + bits_to_f(u2 & 0xffff0000u) +
          bits_to_f(u3 & 0xffff0000u);
  }
  for (; e < end; ++e) {
    unsigned u = Yu[(size_t)srcs[e] * 64 + lane];
    ax += bits_to_f(u << 16);
    ay += bits_to_f(u & 0xffff0000u);
  }
  float sc = scale[node];
  float2 z = ((const float2*)Z)[(size_t)node * 64 + lane];
  float2 b = ((const float2*)bsum)[lane];
  float o0 = fmaxf(z.x + sc * ax + b.x, 0.f);
  float o1 = fmaxf(z.y + sc * ay + b.y, 0.f);
  unsigned short h0 = bf16_rne(o0);
  unsigned short l0 = bf16_rne(o0 - bf16_to_f(h0));
  unsigned short h1 = bf16_rne(o1);
  unsigned short l1 = bf16_rne(o1 - bf16_to_f(h1));
  Hhi[(size_t)node * 64 + lane] = (unsigned)h0 | ((unsigned)h1 << 16);
  Hlo[(size_t)node * 64 + lane] = (unsigned)l0 | ((unsigned)l1 << 16);
}

__global__ LB(256) void agg64_kernel(const ushort* __restrict__ Y, const float* __restrict__ Z,
                                     const int* __restrict__ row_ptr, const int* __restrict__ srcs,
                                     const float* __restrict__ scale, const float* __restrict__ bsum,
                                     float* __restrict__ out, int n) {
  int node = blockIdx.x * 4 + (threadIdx.x >> 6);
  if (node >= n) return;
  int lane = threadIdx.x & 63;
  int e = row_ptr[node], end = row_ptr[node + 1];
  float a = 0.f;
  for (; e + 3 < end; e += 4) {
    int s0 = srcs[e], s1 = srcs[e + 1], s2 = srcs[e + 2], s3 = srcs[e + 3];
    a += bf16_to_f(Y[(size_t)s0 * 64 + lane]) + bf16_to_f(Y[(size_t)s1 * 64 + lane]) +
         bf16_to_f(Y[(size_t)s2 * 64 + lane]) + bf16_to_f(Y[(size_t)s3 * 64 + lane]);
  }
  for (; e < end; ++e) a += bf16_to_f(Y[(size_t)srcs[e] * 64 + lane]);
  float o = Z[(size_t)node * 64 + lane] + scale[node] * a + bsum[lane];
  out[(size_t)node * 64 + lane] = o;
}

// ---------------- launch ----------------
extern "C" void kernel_launch(void* const* d_in, const int* in_sizes, int n_in,
                              void* d_out, int out_size, void* d_ws, size_t ws_size,
                              hipStream_t stream) {
  const float* x = (const float*)d_in[0];
  const int* ei = (const int*)d_in[1];
  const int N = in_sizes[0] / 128;
  const int E = in_sizes[3];
  const int* src = ei;
  const int* dst = ei + E;
  const float* Wl[3] = {(const float*)d_in[4], (const float*)d_in[9], (const float*)d_in[14]};
  const float* bl[3] = {(const float*)d_in[5], (const float*)d_in[10], (const float*)d_in[15]};
  const float* Wr[3] = {(const float*)d_in[6], (const float*)d_in[11], (const float*)d_in[16]};
  const float* Ws[3] = {(const float*)d_in[7], (const float*)d_in[12], (const float*)d_in[17]};
  const float* bs[3] = {(const float*)d_in[8], (const float*)d_in[13], (const float*)d_in[18]};

  const int NB = (N + 255) >> 8;  // 196 buckets

  size_t off = 0;
  auto carve = [&](size_t bytes) -> char* {
    char* p = (char*)d_ws + off;
    off += (bytes + 255) & ~(size_t)255;
    return p;
  };
  int* deg = (int*)carve((size_t)N * 4);
  int* row_ptr = (int*)carve((size_t)(N + 1) * 4);
  int* bsums = (int*)carve(256 * 4);
  int* bcnt = (int*)carve((size_t)NB * 4);
  float* scale = (float*)carve((size_t)N * 4);
  int* srcs = (int*)carve((size_t)E * 4);
  int2* pairs = (int2*)carve((size_t)NB * BCAP * 8);
  ushort* Hhi = (ushort*)carve((size_t)N * 128 * 2);
  ushort* Hlo = (ushort*)carve((size_t)N * 128 * 2);
  ushort* Yb = (ushort*)carve((size_t)N * 128 * 2);
  float* Zf = (float*)carve((size_t)N * 128 * 4);
  ushort* Bh[3];
  ushort* Bo[3];
  float* bsum[3];
  for (int i = 0; i < 3; ++i) {
    Bh[i] = (ushort*)carve(128 * 256 * 2);
    Bo[i] = (ushort*)carve(128 * 256 * 2);
    bsum[i] = (float*)carve(128 * 4);
  }
  (void)ws_size;
  (void)n_in;
  (void)out_size;

  // CSR via bucket sort
  hipMemsetAsync(bcnt, 0, (size_t)NB * 4, stream);
  p1_bucket<<<(E + P1_CHUNK - 1) / P1_CHUNK, 256, 0, stream>>>(src, dst, bcnt, pairs, E);
  p2_hist<<<NB, 256, 0, stream>>>(pairs, bcnt, deg, N);
  int nb = (N + 1023) / 1024;
  scan1_kernel<<<nb, 1024, 0, stream>>>(deg, row_ptr, bsums, N);
  scan2_kernel<<<1, 64, 0, stream>>>(bsums, nb, row_ptr + N);
  scan3_kernel<<<nb, 1024, 0, stream>>>(deg, bsums, row_ptr, scale, N);
  p4_place<<<NB, 256, 0, stream>>>(pairs, bcnt, row_ptr, srcs, N);

  // weights
  wpack_all<<<dim3(128, 3), 256, 0, stream>>>(Wl[0], Wr[0], Ws[0], bl[0], bs[0], Wl[1], Wr[1],
                                              Ws[1], bl[1], bs[1], Wl[2], Wr[2], Ws[2], bl[2],
                                              bs[2], Bh[0], Bo[0], bsum[0], Bh[1], Bo[1], bsum[1],
                                              Bh[2], Bo[2], bsum[2]);

  int g64 = (N + 63) / 64;
  int g128 = (N + 127) / 128;
  int gAgg = (N + 3) / 4;

  // layer 0 (A = fp32 x, split in-reg)
  mfma_gemm_kernel<256, true><<<g64, 256, 0, stream>>>(x, nullptr, nullptr, Bh[0], Bo[0], Yb, Zf, N);
  agg128_kernel<<<gAgg, 256, 0, stream>>>(Yb, Zf, row_ptr, srcs, scale, bsum[0], (unsigned*)Hhi,
                                          (unsigned*)Hlo, N);
  // layer 1
  mfma_gemm_kernel<256, false><<<g64, 256, 0, stream>>>(nullptr, Hhi, Hlo, Bh[1], Bo[1], Yb, Zf, N);
  agg128_kernel<<<gAgg, 256, 0, stream>>>(Yb, Zf, row_ptr, srcs, scale, bsum[1], (unsigned*)Hhi,
                                          (unsigned*)Hlo, N);
  // layer 2
  mfma_gemm_kernel<128, false><<<g128, 256, 0, stream>>>(nullptr, Hhi, Hlo, Bh[2], Bo[2], Yb, Zf, N);
  agg64_kernel<<<gAgg, 256, 0, stream>>>(Yb, Zf, row_ptr, srcs, scale, bsum[2], (float*)d_out, N);
}